// Round 3
// baseline (412.489 us; speedup 1.0000x reference)
//
#include <hip/hip_runtime.h>
#include <hip/hip_bf16.h>

#define NS 8192
#define NF 45
#define ED 256
#define L1K 11520   // 45*256
#define NH 32

typedef __attribute__((ext_vector_type(8))) short bf16x8;
typedef __attribute__((ext_vector_type(4))) float f32x4;

// PERM / FIELD_OFF precomputed from SECTIONS/FEATURE_SIZES
__constant__ int c_perm[NF] = {
    0,1,2,3,4,5,6,7,8,9,
    10,11,12,13,14,15,16,17,18,19,20,21,22,23,
    26,27, 28,29, 24,25,
    30,31,32,33,34,35,36,37,38,39,40,41,42,43,44};
__constant__ int c_foff[NF] = {
    0,300,1300,2300,2800,2950,2962,2993,2993,2993,
    3023,3023,3023,3023,3023,3023,3023,3023,3023,3023,3023,3023,3023,3023,
    3223,3223, 53223,53223, 103223,103223,
    123223,123223,123223,123223,123223,123223,123223,123223,
    123223,123223,123223,123223,123223,123223,123223};

__device__ __forceinline__ short f2bf(float x) {
    unsigned u = __builtin_bit_cast(unsigned, x);
    u += 0x7fffu + ((u >> 16) & 1u);   // round-to-nearest-even
    return (short)(u >> 16);
}

// packed f32x2 -> bf16x2 (RNE), single instruction on gfx950
__device__ __forceinline__ unsigned pk_bf16(float a, float b) {
    unsigned r;
    asm("v_cvt_pk_bf16_f32 %0, %1, %2" : "=v"(r) : "v"(a), "v"(b));
    return r;
}

// ---------------- kernel 0: pack l1_w into bf16 B-fragment layout --------
// BFRAG[((f*8+ks)*2+nt)*512 + l*8 + i] = bf16( l1w[nt*16+(l&15)][f*256+ks*32+(l>>4)*8+i] )
// Block 0 additionally zero-inits S1[32] + S2[1024] (consumed by k_main's atomics).
__global__ __launch_bounds__(256) void k_pack(const float* __restrict__ l1w,
                                              short* __restrict__ bfrag,
                                              float* __restrict__ S1) {
    int t = blockIdx.x * 256 + threadIdx.x;
    if (blockIdx.x == 0) {
        for (int i = threadIdx.x; i < NH + NH * NH; i += 256) S1[i] = 0.f;
    }
    if (t >= NF * 8192) return;
    int i  = t & 7;
    int l  = (t >> 3) & 63;
    int nt = (t >> 9) & 1;
    int ks = (t >> 10) & 7;
    int f  = t >> 13;
    int kout = nt * 16 + (l & 15);
    int col  = f * 256 + ks * 32 + (l >> 4) * 8 + i;
    bfrag[t] = f2bf(l1w[kout * L1K + col]);
}

// ---------------- kernel 1: fused gather + FM + deep GEMM + batch stats --
// 512 blocks x 256 thr. Block owns 16 samples (full 256 embed dims);
// 4 waves split K (2 MFMA k-steps each). Epilogue: h1pre out, fm partials,
// and atomic accumulation of S1[32] / S2[32x32] batch moments.
__global__ __launch_bounds__(256) void k_main(const float* __restrict__ W2,
                                              const float* __restrict__ W1,
                                              const int* __restrict__ Xi,
                                              const float* __restrict__ Xv,
                                              const short* __restrict__ bfrag,
                                              float* __restrict__ h1pre,
                                              float* __restrict__ partial,
                                              float* __restrict__ S1,
                                              float* __restrict__ S2) {
    __shared__ int   s_idx[16 * NF];
    __shared__ float s_xv [16 * NF];
    __shared__ float s_red[4 * 16 * NH];   // 8 KB wave partials of h1pre
    __shared__ float s_h[16 * NH];         // 2 KB combined h1pre tile
    __shared__ float s_q[4][16];
    __shared__ float s_fm1[16];

    const int tid = threadIdx.x;
    const int w = tid >> 6;
    const int l = tid & 63;
    const int m = l & 15;          // sample-local (MFMA M index)
    const int g4 = l >> 4;         // k-quad within fragment
    const int n0 = blockIdx.x * 16;

    for (int t = tid; t < 16 * NF; t += 256) {
        int f = t % NF;
        int n = n0 + t / NF;
        int col = c_perm[f];
        s_idx[t] = Xi[n * NF + col] + c_foff[f];
        s_xv[t]  = Xv[n * NF + col];
    }
    __syncthreads();

    const int ks0 = w * 2;
    f32x4 acc0 = {0.f, 0.f, 0.f, 0.f};
    f32x4 acc1 = {0.f, 0.f, 0.f, 0.f};
    float sA[16];
    #pragma unroll
    for (int i = 0; i < 16; ++i) sA[i] = 0.f;
    float esq = 0.f, fm1 = 0.f;

    const short* bbase = bfrag + (size_t)(ks0 * 2) * 512 + l * 8;

    for (int f = 0; f < NF; ++f) {
        const int   idx = s_idx[m * NF + f];
        const float xv  = s_xv [m * NF + f];
        const float* wr = W2 + (size_t)idx * ED + ks0 * 32 + g4 * 8;

        f32x4 a0 = *(const f32x4*)(wr);
        f32x4 a1 = *(const f32x4*)(wr + 4);
        f32x4 a2 = *(const f32x4*)(wr + 32);
        f32x4 a3 = *(const f32x4*)(wr + 36);

        const short* bp = bbase + (size_t)f * 8192;
        bf16x8 b00 = *(const bf16x8*)(bp);          // kstep ks0,  ntile 0
        bf16x8 b01 = *(const bf16x8*)(bp + 512);    // kstep ks0,  ntile 1
        bf16x8 b10 = *(const bf16x8*)(bp + 1024);   // kstep ks0+1,ntile 0
        bf16x8 b11 = *(const bf16x8*)(bp + 1536);   // kstep ks0+1,ntile 1

        float e[16];
        e[0]=a0.x*xv; e[1]=a0.y*xv; e[2]=a0.z*xv; e[3]=a0.w*xv;
        e[4]=a1.x*xv; e[5]=a1.y*xv; e[6]=a1.z*xv; e[7]=a1.w*xv;
        e[8]=a2.x*xv; e[9]=a2.y*xv; e[10]=a2.z*xv; e[11]=a2.w*xv;
        e[12]=a3.x*xv; e[13]=a3.y*xv; e[14]=a3.z*xv; e[15]=a3.w*xv;

        #pragma unroll
        for (int i = 0; i < 16; ++i) { sA[i] += e[i]; esq += e[i] * e[i]; }

        union { bf16x8 v; unsigned u[4]; } A0, A1;
        A0.u[0] = pk_bf16(e[0],  e[1]);
        A0.u[1] = pk_bf16(e[2],  e[3]);
        A0.u[2] = pk_bf16(e[4],  e[5]);
        A0.u[3] = pk_bf16(e[6],  e[7]);
        A1.u[0] = pk_bf16(e[8],  e[9]);
        A1.u[1] = pk_bf16(e[10], e[11]);
        A1.u[2] = pk_bf16(e[12], e[13]);
        A1.u[3] = pk_bf16(e[14], e[15]);

        acc0 = __builtin_amdgcn_mfma_f32_16x16x32_bf16(A0.v, b00, acc0, 0, 0, 0);
        acc1 = __builtin_amdgcn_mfma_f32_16x16x32_bf16(A0.v, b01, acc1, 0, 0, 0);
        acc0 = __builtin_amdgcn_mfma_f32_16x16x32_bf16(A1.v, b10, acc0, 0, 0, 0);
        acc1 = __builtin_amdgcn_mfma_f32_16x16x32_bf16(A1.v, b11, acc1, 0, 0, 0);

        if (w == 0) fm1 += W1[idx] * xv;   // wave-uniform branch
    }

    // fm2 partial: sum(s^2) - sum(e^2) over this lane's j's
    float q = -esq;
    #pragma unroll
    for (int i = 0; i < 16; ++i) q += sA[i] * sA[i];
    q += __shfl_xor(q, 16);
    q += __shfl_xor(q, 32);
    if (l < 16) s_q[w][l] = q;
    if (w == 0 && l < 16) s_fm1[l] = fm1;

    // stash wave-partial h1pre (D layout: row=(l>>4)*4+r, col=l&15)
    #pragma unroll
    for (int r = 0; r < 4; ++r) {
        s_red[w * 512 + (g4 * 4 + r) * 32 +      m] = acc0[r];
        s_red[w * 512 + (g4 * 4 + r) * 32 + 16 + m] = acc1[r];
    }
    __syncthreads();

    for (int t = tid; t < 512; t += 256) {
        float v = s_red[t] + s_red[512 + t] + s_red[1024 + t] + s_red[1536 + t];
        h1pre[(size_t)n0 * NH + t] = v;   // t = s*32 + k, contiguous
        s_h[t] = v;
    }
    if (tid < 16) {
        float fm2 = 0.5f * (s_q[0][tid] + s_q[1][tid] + s_q[2][tid] + s_q[3][tid]);
        partial[n0 + tid] = s_fm1[tid] + fm2;
    }
    __syncthreads();

    // batch-moment partials for BN folding: S1 += sum_s h, S2 += h h^T
    {
        const int j  = tid >> 3;
        const int k4 = (tid & 7) * 4;
        float a0 = 0.f, a1 = 0.f, a2 = 0.f, a3 = 0.f;
        #pragma unroll
        for (int s = 0; s < 16; ++s) {
            float hj = s_h[s * NH + j];
            f32x4 h = *(const f32x4*)&s_h[s * NH + k4];
            a0 += hj * h.x; a1 += hj * h.y; a2 += hj * h.z; a3 += hj * h.w;
        }
        atomicAdd(&S2[j * NH + k4 + 0], a0);
        atomicAdd(&S2[j * NH + k4 + 1], a1);
        atomicAdd(&S2[j * NH + k4 + 2], a2);
        atomicAdd(&S2[j * NH + k4 + 3], a3);
        if (tid < NH) {
            float s1 = 0.f;
            #pragma unroll
            for (int s = 0; s < 16; ++s) s1 += s_h[s * NH + tid];
            atomicAdd(&S1[tid], s1);
        }
    }
}

// ---------------- kernel 2: BN fold (redundant per block) + finalize -----
__global__ __launch_bounds__(256) void k_cf(const float* __restrict__ S1,
                                            const float* __restrict__ S2,
                                            const float* __restrict__ g1,
                                            const float* __restrict__ l2w,
                                            const float* __restrict__ g2,
                                            const float* __restrict__ b2,
                                            const float* __restrict__ bias,
                                            const float* __restrict__ h1pre,
                                            const float* __restrict__ partial,
                                            float* __restrict__ out) {
    __shared__ float sS2[NH * NH];
    __shared__ float m1[NH], d1[NH], g2r2[NH], csh[NH];
    __shared__ float k0s;
    const int t = threadIdx.x;
    const float invN = 1.f / (float)NS;

    for (int i = t; i < NH * NH; i += 256) sS2[i] = S2[i];
    __syncthreads();
    if (t < NH) {
        float mm = S1[t] * invN;
        float v1 = sS2[t * NH + t] * invN - mm * mm;
        m1[t] = mm;
        d1[t] = g1[t] * rsqrtf(v1 + 1e-5f);
    }
    __syncthreads();
    if (t < NH) {
        float aw[NH];
        float p = 0.f;
        for (int j = 0; j < NH; ++j) { aw[j] = l2w[t * NH + j] * d1[j]; p += aw[j] * m1[j]; }
        float v2 = 0.f;
        for (int j = 0; j < NH; ++j) {
            float acc = 0.f;
            for (int j2 = 0; j2 < NH; ++j2) acc += aw[j2] * sS2[j * NH + j2];
            v2 += aw[j] * acc;
        }
        v2 = v2 * invN - p * p;
        g2r2[t] = g2[t] * rsqrtf(v2 + 1e-5f);
    }
    __syncthreads();
    if (t < NH) {
        float s = 0.f;
        for (int k = 0; k < NH; ++k) s += g2r2[k] * l2w[k * NH + t];
        csh[t] = d1[t] * s;
    }
    __syncthreads();
    if (t == 0) {
        float k0 = bias[0];
        for (int k = 0; k < NH; ++k) k0 += b2[k];
        for (int j = 0; j < NH; ++j) k0 -= csh[j] * m1[j];
        k0s = k0;
    }
    __syncthreads();

    const int n = blockIdx.x * 256 + t;
    const f32x4* hp = (const f32x4*)(h1pre + (size_t)n * NH);
    float dot = 0.f;
    #pragma unroll
    for (int q = 0; q < 8; ++q) {
        f32x4 h = hp[q];
        dot += h.x * csh[q * 4] + h.y * csh[q * 4 + 1]
             + h.z * csh[q * 4 + 2] + h.w * csh[q * 4 + 3];
    }
    out[n] = partial[n] + dot + k0s;
}

extern "C" void kernel_launch(void* const* d_in, const int* in_sizes, int n_in,
                              void* d_out, int out_size, void* d_ws, size_t ws_size,
                              hipStream_t stream) {
    const int*   Xi   = (const int*)  d_in[0];
    const float* Xv   = (const float*)d_in[1];
    const float* W1   = (const float*)d_in[2];
    const float* W2   = (const float*)d_in[3];
    const float* bias = (const float*)d_in[4];
    const float* l1w  = (const float*)d_in[5];
    // d_in[6] = l1_b  (cancels under BN)
    const float* g1   = (const float*)d_in[7];
    // d_in[8] = bn1_b (cancels)
    const float* l2w  = (const float*)d_in[9];
    // d_in[10] = l2_b (cancels)
    const float* g2   = (const float*)d_in[11];
    const float* b2   = (const float*)d_in[12];
    float* out = (float*)d_out;

    char* ws = (char*)d_ws;
    short* bfrag = (short*)ws;                          // 368640 bf16
    float* h1    = (float*)(ws + (size_t)368640 * 2);   // 8192*32 f
    float* part  = h1 + (size_t)NS * NH;                // 8192 f
    float* S1    = part + NS;                           // 32 (then S2 1024)
    float* S2    = S1 + NH;

    k_pack<<<(NF * 8192 + 255) / 256, 256, 0, stream>>>(l1w, bfrag, S1);
    k_main<<<NS / 16, 256, 0, stream>>>(W2, W1, Xi, Xv, bfrag, h1, part, S1, S2);
    k_cf  <<<NS / 256, 256, 0, stream>>>(S1, S2, g1, l2w, g2, b2, bias, h1, part, out);
}

// Round 5
// 381.753 us; speedup vs baseline: 1.0805x; 1.0805x over previous
//
#include <hip/hip_runtime.h>
#include <hip/hip_bf16.h>

#define NS 8192
#define NF 45
#define ED 256
#define L1K 11520   // 45*256
#define NH 32

typedef __attribute__((ext_vector_type(8))) short bf16x8;
typedef __attribute__((ext_vector_type(4))) float f32x4;
typedef __attribute__((ext_vector_type(4))) unsigned uint32x4;

// PERM / FIELD_OFF precomputed from SECTIONS/FEATURE_SIZES
__constant__ int c_perm[NF] = {
    0,1,2,3,4,5,6,7,8,9,
    10,11,12,13,14,15,16,17,18,19,20,21,22,23,
    26,27, 28,29, 24,25,
    30,31,32,33,34,35,36,37,38,39,40,41,42,43,44};
__constant__ int c_foff[NF] = {
    0,300,1300,2300,2800,2950,2962,2993,2993,2993,
    3023,3023,3023,3023,3023,3023,3023,3023,3023,3023,3023,3023,3023,3023,
    3223,3223, 53223,53223, 103223,103223,
    123223,123223,123223,123223,123223,123223,123223,123223,
    123223,123223,123223,123223,123223,123223,123223};

__device__ __forceinline__ short f2bf(float x) {
    unsigned u = __builtin_bit_cast(unsigned, x);
    u += 0x7fffu + ((u >> 16) & 1u);   // round-to-nearest-even
    return (short)(u >> 16);
}

// packed f32x2 -> bf16x2 (RNE), single instruction on gfx950
__device__ __forceinline__ unsigned pk_bf16(float a, float b) {
    unsigned r;
    asm("v_cvt_pk_bf16_f32 %0, %1, %2" : "=v"(r) : "v"(a), "v"(b));
    return r;
}

// ---------------- kernel 0: pack l1_w into bf16 B-fragment layout --------
// BFRAG[((f*8+ks)*2+nt)*512 + l*8 + i] = bf16( l1w[nt*16+(l&15)][f*256+ks*32+(l>>4)*8+i] )
__global__ __launch_bounds__(256) void k_pack(const float* __restrict__ l1w,
                                              short* __restrict__ bfrag) {
    int t = blockIdx.x * 256 + threadIdx.x;
    if (t >= NF * 8192) return;
    int i  = t & 7;
    int l  = (t >> 3) & 63;
    int nt = (t >> 9) & 1;
    int ks = (t >> 10) & 7;
    int f  = t >> 13;
    int kout = nt * 16 + (l & 15);
    int col  = f * 256 + ks * 32 + (l >> 4) * 8 + i;
    bfrag[t] = f2bf(l1w[kout * L1K + col]);
}

// ---------------- kernel 1: fused gather + FM + deep GEMM ----------------
// 1024 blocks x 256 thr. Block pair (bx>>1) owns 16 samples; half = bx&1
// covers 128 embed dims; each of 4 waves covers one 32-dim MFMA k-step.
// Scalar rotating depth-1 prefetch: f+1's loads issue before f's MFMA.
__global__ __launch_bounds__(256) void k_main(const float* __restrict__ W2,
                                              const float* __restrict__ W1,
                                              const int* __restrict__ Xi,
                                              const float* __restrict__ Xv,
                                              const short* __restrict__ bfrag,
                                              float* __restrict__ h1h,     // [2][NS][NH]
                                              float* __restrict__ parth) { // [2][NS]
    __shared__ int   s_idx[16 * NF];
    __shared__ float s_xv [16 * NF];
    __shared__ float s_red[4 * 16 * NH];   // 8 KB wave partials of h1pre
    __shared__ float s_q[4][16];
    __shared__ float s_fm1[16];

    const int tid  = threadIdx.x;
    const int w    = tid >> 6;
    const int l    = tid & 63;
    const int m    = l & 15;       // sample-local (MFMA M index)
    const int g4   = l >> 4;       // k-quad within fragment
    const int half = blockIdx.x & 1;
    const int n0   = (blockIdx.x >> 1) * 16;
    const int ks   = half * 4 + w; // this wave's MFMA k-step (0..7)

    for (int t = tid; t < 16 * NF; t += 256) {
        int f = t % NF;
        int n = n0 + t / NF;
        int col = c_perm[f];
        s_idx[t] = Xi[n * NF + col] + c_foff[f];
        s_xv[t]  = Xv[n * NF + col];
    }
    __syncthreads();

    f32x4 acc0 = {0.f, 0.f, 0.f, 0.f};
    f32x4 acc1 = {0.f, 0.f, 0.f, 0.f};
    float sA[8];
    #pragma unroll
    for (int i = 0; i < 8; ++i) sA[i] = 0.f;
    float esq = 0.f, fm1 = 0.f;

    const short* bbase = bfrag + (size_t)ks * 1024 + l * 8;
    const float* wbase = W2 + ks * 32 + g4 * 8;
    const bool  isw0   = (half == 0 && w == 0);

    // ---- prologue: load f = 0 into current regs ----
    int   idx_c = s_idx[m * NF + 0];
    float xv_c  = s_xv [m * NF + 0];
    const float* wr0 = wbase + (size_t)idx_c * ED;
    f32x4  a0_c = *(const f32x4*)(wr0);
    f32x4  a1_c = *(const f32x4*)(wr0 + 4);
    bf16x8 b0_c = *(const bf16x8*)(bbase);
    bf16x8 b1_c = *(const bf16x8*)(bbase + 512);
    float  w1_c = isw0 ? W1[idx_c] : 0.f;

    for (int f = 0; f < NF; ++f) {
        // issue next iteration's loads first (in flight across this MFMA)
        f32x4  a0_n, a1_n;
        bf16x8 b0_n, b1_n;
        float  xv_n, w1_n;
        const bool more = (f + 1 < NF);
        if (more) {
            int idx_n = s_idx[m * NF + f + 1];
            xv_n = s_xv[m * NF + f + 1];
            const float* wr = wbase + (size_t)idx_n * ED;
            a0_n = *(const f32x4*)(wr);
            a1_n = *(const f32x4*)(wr + 4);
            const short* bp = bbase + (size_t)(f + 1) * 8192;
            b0_n = *(const bf16x8*)(bp);
            b1_n = *(const bf16x8*)(bp + 512);
            w1_n = isw0 ? W1[idx_n] : 0.f;
        }

        float e[8];
        e[0] = a0_c.x * xv_c; e[1] = a0_c.y * xv_c;
        e[2] = a0_c.z * xv_c; e[3] = a0_c.w * xv_c;
        e[4] = a1_c.x * xv_c; e[5] = a1_c.y * xv_c;
        e[6] = a1_c.z * xv_c; e[7] = a1_c.w * xv_c;

        #pragma unroll
        for (int i = 0; i < 8; ++i) { sA[i] += e[i]; esq += e[i] * e[i]; }

        uint32x4 au;
        au.x = pk_bf16(e[0], e[1]);
        au.y = pk_bf16(e[2], e[3]);
        au.z = pk_bf16(e[4], e[5]);
        au.w = pk_bf16(e[6], e[7]);
        bf16x8 Af = __builtin_bit_cast(bf16x8, au);

        acc0 = __builtin_amdgcn_mfma_f32_16x16x32_bf16(Af, b0_c, acc0, 0, 0, 0);
        acc1 = __builtin_amdgcn_mfma_f32_16x16x32_bf16(Af, b1_c, acc1, 0, 0, 0);

        fm1 += w1_c * xv_c;    // w1_c == 0 except half 0 / wave 0

        if (more) {   // rotate
            a0_c = a0_n; a1_c = a1_n;
            b0_c = b0_n; b1_c = b1_n;
            xv_c = xv_n; w1_c = w1_n;
        }
    }

    // fm2 partial over this block's 128 j's: sum(sA^2) - sum(e^2)
    float q = -esq;
    #pragma unroll
    for (int i = 0; i < 8; ++i) q += sA[i] * sA[i];
    q += __shfl_xor(q, 16);
    q += __shfl_xor(q, 32);
    if (l < 16) s_q[w][l] = q;
    if (w == 0 && l < 16) s_fm1[l] = fm1;   // zero for half==1

    // stash wave-partial h1pre (D layout: sample=(l>>4)*4+r, j=l&15 [+16 for acc1])
    #pragma unroll
    for (int r = 0; r < 4; ++r) {
        s_red[w * 512 + (g4 * 4 + r) * 32 +      m] = acc0[r];
        s_red[w * 512 + (g4 * 4 + r) * 32 + 16 + m] = acc1[r];
    }
    __syncthreads();

    float* h1out = h1h + (size_t)half * NS * NH;
    for (int t = tid; t < 512; t += 256) {
        float v = s_red[t] + s_red[512 + t] + s_red[1024 + t] + s_red[1536 + t];
        h1out[(size_t)n0 * NH + t] = v;   // t = s*32 + k, contiguous
    }
    if (tid < 16) {
        float fm2 = 0.5f * (s_q[0][tid] + s_q[1][tid] + s_q[2][tid] + s_q[3][tid]);
        parth[half * NS + n0 + tid] = s_fm1[tid] + fm2;
    }
}

// ---------------- kernel 2: S1[32], S2[32][32] over the batch ------------
__global__ __launch_bounds__(256) void k_stats(const float* __restrict__ h1h,
                                               float* __restrict__ S1,
                                               float* __restrict__ S2) {
    __shared__ float hc[128 * NH];   // 16 KB
    const int tid = threadIdx.x;
    const int base = blockIdx.x * 128;   // 64 blocks
    for (int t = tid; t < 128 * NH; t += 256)
        hc[t] = h1h[(size_t)base * NH + t] + h1h[(size_t)NS * NH + base * NH + t];
    __syncthreads();

    const int j = tid >> 3;
    const int ks = (tid & 7) * 4;
    float a0 = 0.f, a1 = 0.f, a2 = 0.f, a3 = 0.f;
    for (int n = 0; n < 128; ++n) {
        float hj = hc[n * NH + j];
        f32x4 h = *(const f32x4*)&hc[n * NH + ks];
        a0 += hj * h.x; a1 += hj * h.y; a2 += hj * h.z; a3 += hj * h.w;
    }
    atomicAdd(&S2[j * NH + ks + 0], a0);
    atomicAdd(&S2[j * NH + ks + 1], a1);
    atomicAdd(&S2[j * NH + ks + 2], a2);
    atomicAdd(&S2[j * NH + ks + 3], a3);
    if (tid < NH) {
        float s = 0.f;
        for (int n = 0; n < 128; ++n) s += hc[n * NH + tid];
        atomicAdd(&S1[tid], s);
    }
}

// ---------------- kernel 3: analytic BN folding -> c[32], K0 -------------
__global__ __launch_bounds__(256) void k_coef(const float* __restrict__ S1,
                                              const float* __restrict__ S2,
                                              const float* __restrict__ g1,
                                              const float* __restrict__ l2w,
                                              const float* __restrict__ g2,
                                              const float* __restrict__ b2,
                                              const float* __restrict__ bias,
                                              float* __restrict__ cvec,
                                              float* __restrict__ k0out) {
    __shared__ float m1[NH], d1[NH], g2r2[NH], csh[NH];
    const int t = threadIdx.x;
    const float invN = 1.f / (float)NS;
    if (t < NH) {
        float mm = S1[t] * invN;
        float v1 = S2[t * NH + t] * invN - mm * mm;
        m1[t] = mm;
        d1[t] = g1[t] * rsqrtf(v1 + 1e-5f);
    }
    __syncthreads();
    if (t < NH) {
        float aw[NH];
        float p = 0.f;
        for (int j = 0; j < NH; ++j) { aw[j] = l2w[t * NH + j] * d1[j]; p += aw[j] * m1[j]; }
        float v2 = 0.f;
        for (int j = 0; j < NH; ++j) {
            float acc = 0.f;
            for (int j2 = 0; j2 < NH; ++j2) acc += aw[j2] * S2[j * NH + j2];
            v2 += aw[j] * acc;
        }
        v2 = v2 * invN - p * p;
        g2r2[t] = g2[t] * rsqrtf(v2 + 1e-5f);
    }
    __syncthreads();
    if (t < NH) {
        float s = 0.f;
        for (int k = 0; k < NH; ++k) s += g2r2[k] * l2w[k * NH + t];
        float c = d1[t] * s;
        csh[t] = c;
        cvec[t] = c;
    }
    __syncthreads();
    if (t == 0) {
        float k0 = bias[0];
        for (int k = 0; k < NH; ++k) k0 += b2[k];
        for (int j = 0; j < NH; ++j) k0 -= csh[j] * m1[j];
        k0out[0] = k0;
    }
}

// ---------------- kernel 4: finalize -------------------------------------
__global__ __launch_bounds__(256) void k_final(const float* __restrict__ h1h,
                                               const float* __restrict__ parth,
                                               const float* __restrict__ cvec,
                                               const float* __restrict__ k0p,
                                               float* __restrict__ out) {
    __shared__ float c[NH];
    __shared__ float k0s;
    const int t = threadIdx.x;
    if (t < NH) c[t] = cvec[t];
    if (t == 0) k0s = k0p[0];
    __syncthreads();
    const int n = blockIdx.x * 256 + t;
    const f32x4* hp0 = (const f32x4*)(h1h + (size_t)n * NH);
    const f32x4* hp1 = (const f32x4*)(h1h + (size_t)NS * NH + (size_t)n * NH);
    float dot = 0.f;
    #pragma unroll
    for (int q = 0; q < 8; ++q) {
        f32x4 h0 = hp0[q];
        f32x4 h1 = hp1[q];
        dot += (h0.x + h1.x) * c[q * 4]     + (h0.y + h1.y) * c[q * 4 + 1]
             + (h0.z + h1.z) * c[q * 4 + 2] + (h0.w + h1.w) * c[q * 4 + 3];
    }
    out[n] = parth[n] + parth[NS + n] + dot + k0s;
}

extern "C" void kernel_launch(void* const* d_in, const int* in_sizes, int n_in,
                              void* d_out, int out_size, void* d_ws, size_t ws_size,
                              hipStream_t stream) {
    const int*   Xi   = (const int*)  d_in[0];
    const float* Xv   = (const float*)d_in[1];
    const float* W1   = (const float*)d_in[2];
    const float* W2   = (const float*)d_in[3];
    const float* bias = (const float*)d_in[4];
    const float* l1w  = (const float*)d_in[5];
    // d_in[6] = l1_b  (cancels under BN)
    const float* g1   = (const float*)d_in[7];
    // d_in[8] = bn1_b (cancels)
    const float* l2w  = (const float*)d_in[9];
    // d_in[10] = l2_b (cancels)
    const float* g2   = (const float*)d_in[11];
    const float* b2   = (const float*)d_in[12];
    float* out = (float*)d_out;

    char* ws = (char*)d_ws;
    short* bfrag = (short*)ws;                         // 368640 bf16
    float* h1h   = (float*)(ws + (size_t)368640 * 2);  // 2*8192*32 f
    float* parth = h1h + (size_t)2 * NS * NH;          // 2*8192 f
    float* S1    = parth + 2 * NS;                     // 32
    float* S2    = S1 + NH;                            // 1024
    float* cvec  = S2 + NH * NH;                       // 32
    float* k0p   = cvec + NH;                          // 1

    hipMemsetAsync(S1, 0, (NH + NH * NH) * sizeof(float), stream);
    k_pack <<<(NF * 8192 + 255) / 256, 256, 0, stream>>>(l1w, bfrag);
    k_main <<<NS / 16 * 2, 256, 0, stream>>>(W2, W1, Xi, Xv, bfrag, h1h, parth);
    k_stats<<<64, 256, 0, stream>>>(h1h, S1, S2);
    k_coef <<<1, 256, 0, stream>>>(S1, S2, g1, l2w, g2, b2, bias, cvec, k0p);
    k_final<<<NS / 256, 256, 0, stream>>>(h1h, parth, cvec, k0p, out);
}